// Round 10
// baseline (164.411 us; speedup 1.0000x reference)
//
#include <hip/hip_runtime.h>
#include <hip/hip_bf16.h>

#define NN 50000
#define NE 800000
#define NC 128
#define NEG 0.2f
#define BN_EPS 1e-5f
#define NB 391           // ceil(NN/128) dst-buckets, 128 nodes each
#define EPB 2048         // edges per binning block
#define DEPTH 16         // LDS staging depth per bucket (flush = 64B line)

typedef unsigned int u32;
typedef unsigned short u16;
typedef short bf16x8 __attribute__((ext_vector_type(8)));
typedef float f32x4 __attribute__((ext_vector_type(4)));

// workspace layout (4-byte units)
#define OFF_H       0          // NN*NC bf16
#define OFF_ACCUM   3200000    // NN*NC f32
#define OFF_ASRC    9600000    // NN
#define OFF_ADST    9650000    // NN
#define OFF_BCNT    9700000    // 512   <- zeroed (in k_prep) from here
#define OFF_GCUR    9700512    // 512
#define OFF_GSUM    9701024    // 128
#define OFF_GSUMSQ  9701152    // 128   <- zeroed to here (1280 words)
#define OFF_BBASE   9701280    // 400 (NB+1)
#define OFF_ROWPTR  9701680    // NN+1
#define OFF_ESRC    9751688    // NE
#define OFF_WGT     10551688   // NE
#define OFF_BIN     11351688   // NE
#define OFF_WB      12151688   // 8192 u32 (W in bf16 MFMA-frag order, 32 KB)
#define OFF_END     12159880   // ~48.6 MB
#define NZERO       1280       // words zeroed each launch starting at OFF_BCNT

__device__ __forceinline__ float leaky(float e) { return (e >= 0.f) ? e : NEG * e; }

__device__ __forceinline__ u16 f2b(float f) {   // fp32 -> bf16 RNE
  union { float f; u32 u; } v; v.f = f;
  u32 u = v.u;
  return (u16)((u + 0x7fffu + ((u >> 16) & 1u)) >> 16);
}
__device__ __forceinline__ float blo(u32 u) {
  union { u32 u; float f; } v; v.u = u << 16; return v.f;
}
__device__ __forceinline__ float bhi(u32 u) {
  union { u32 u; float f; } v; v.u = u & 0xffff0000u; return v.f;
}

__device__ __forceinline__ bool ei_is64(const void* ei_raw) {
  const unsigned long long* p64 = (const unsigned long long*)ei_raw;
  bool is64 = true;
#pragma unroll
  for (int k = 0; k < 8; ++k) is64 = is64 && (p64[k] < (unsigned long long)NN);
  return is64;
}

// ---- pack W into MFMA B-fragment order (bf16) + zero the counter region ---
// frag f = n*4+s holds cols 16n..16n+15, k = 32s..32s+31.
// lane l of frag f: col = 16n+(l&15), k = 32s+8*(l>>4)+j (j=0..7).
__global__ __launch_bounds__(256) void k_prep(
    const float* __restrict__ W, u32* __restrict__ Wb32, int* __restrict__ zbase) {
  if (blockIdx.x == 0) {
    for (int i = threadIdx.x; i < NZERO; i += 256) zbase[i] = 0;
  }
  int q = blockIdx.x * 256 + threadIdx.x;   // 2048 slots
  if (q >= 2048) return;
  int f = q >> 6, l = q & 63;
  int n = f >> 2, s = f & 3;
  int col = 16 * n + (l & 15);
  int kb = 32 * s + 8 * (l >> 4);
#pragma unroll
  for (int j2 = 0; j2 < 4; ++j2) {
    u16 e0 = f2b(W[(kb + 2 * j2) * NC + col]);
    u16 e1 = f2b(W[(kb + 2 * j2 + 1) * NC + col]);
    Wb32[q * 4 + j2] = ((u32)e1 << 16) | e0;
  }
}

// ---- h = x@W via MFMA bf16, B-frags from global (no LDS, no syncs) --------
__global__ __launch_bounds__(256) void k_gemm(
    const float* __restrict__ x, const u16* __restrict__ Wb,
    const float* __restrict__ attS, const float* __restrict__ attD,
    u16* __restrict__ h, float* __restrict__ a_src, float* __restrict__ a_dst) {
  const int t = threadIdx.x;
  const int l = t & 63;
  const int r0 = blockIdx.x * 128 + (t >> 6) * 32;
  const int lr = l & 15;                  // row-in-tile / col-in-frag
  const int kg = l >> 4;                  // k-group

  f32x4 acc[2][8];
#pragma unroll
  for (int t2 = 0; t2 < 2; ++t2)
#pragma unroll
    for (int n = 0; n < 8; ++n) acc[t2][n] = (f32x4){0.f, 0.f, 0.f, 0.f};

#pragma unroll
  for (int s = 0; s < 4; ++s) {
    bf16x8 bfr[8];
#pragma unroll
    for (int n = 0; n < 8; ++n)
      bfr[n] = *(const bf16x8*)(Wb + ((size_t)((n * 4 + s) * 64 + l)) * 8);

#pragma unroll
    for (int t2 = 0; t2 < 2; ++t2) {
      int arow = r0 + t2 * 16 + lr;
      f32x4 a0 = (f32x4){0.f,0.f,0.f,0.f}, a1 = a0;
      if (arow < NN) {
        const float* xa = x + (size_t)arow * NC + kg * 8 + s * 32;
        a0 = *(const f32x4*)xa;
        a1 = *(const f32x4*)(xa + 4);
      }
      bf16x8 af;
      af[0]=(short)f2b(a0[0]); af[1]=(short)f2b(a0[1]);
      af[2]=(short)f2b(a0[2]); af[3]=(short)f2b(a0[3]);
      af[4]=(short)f2b(a1[0]); af[5]=(short)f2b(a1[1]);
      af[6]=(short)f2b(a1[2]); af[7]=(short)f2b(a1[3]);
#pragma unroll
      for (int n = 0; n < 8; ++n)
        acc[t2][n] = __builtin_amdgcn_mfma_f32_16x16x32_bf16(af, bfr[n], acc[t2][n], 0, 0, 0);
    }
  }

  float attS_r[8], attD_r[8];
#pragma unroll
  for (int n = 0; n < 8; ++n) {
    attS_r[n] = attS[16 * n + lr];
    attD_r[n] = attD[16 * n + lr];
  }
#pragma unroll
  for (int t2 = 0; t2 < 2; ++t2) {
#pragma unroll
    for (int q = 0; q < 4; ++q) {
      int row = r0 + t2 * 16 + kg * 4 + q;
      bool rok = row < NN;
      float sA = 0.f, sD = 0.f;
#pragma unroll
      for (int n = 0; n < 8; ++n) {
        float v = acc[t2][n][q];
        sA += v * attS_r[n];
        sD += v * attD_r[n];
        if (rok) h[(size_t)row * NC + 16 * n + lr] = f2b(v);
      }
      sA += __shfl_xor(sA, 1); sD += __shfl_xor(sD, 1);
      sA += __shfl_xor(sA, 2); sD += __shfl_xor(sD, 2);
      sA += __shfl_xor(sA, 4); sD += __shfl_xor(sD, 4);
      sA += __shfl_xor(sA, 8); sD += __shfl_xor(sD, 8);
      if (lr == 0 && rok) { a_src[row] = sA; a_dst[row] = sD; }
    }
  }
}

// ---- bucket histogram (LDS-staged) ----------------------------------------
__global__ __launch_bounds__(256) void k_bhist(
    const void* __restrict__ ei_raw, int* __restrict__ bcnt) {
  __shared__ int cnt[NB];
  int t = threadIdx.x;
  for (int i = t; i < NB; i += 256) cnt[i] = 0;
  __syncthreads();
  bool is64 = ei_is64(ei_raw);
  int base = blockIdx.x * EPB;
#pragma unroll
  for (int k = 0; k < 8; ++k) {
    int idx = base + k * 256 + t;
    if (idx < NE) {
      int d = is64 ? (int)((const long long*)ei_raw)[NE + idx]
                   : ((const int*)ei_raw)[NE + idx];
      atomicAdd(&cnt[d >> 7], 1);
    }
  }
  __syncthreads();
  for (int i = t; i < NB; i += 256)
    if (cnt[i] > 0) atomicAdd(&bcnt[i], cnt[i]);
}

// ---- bucket-base exclusive scan (one block) -------------------------------
__global__ __launch_bounds__(512) void k_bscan(
    const int* __restrict__ bcnt, int* __restrict__ bbase) {
  __shared__ int sh[512];
  int t = threadIdx.x;
  int v = (t < NB) ? bcnt[t] : 0;
  sh[t] = v;
  __syncthreads();
  for (int off = 1; off < 512; off <<= 1) {
    int xv = (t >= off) ? sh[t - off] : 0;
    __syncthreads();
    sh[t] += xv;
    __syncthreads();
  }
  if (t <= NB) bbase[t] = sh[t] - v;   // exclusive; bbase[NB] = NE
}

// ---- bin edges into buckets, LDS-staged coalesced flushes -----------------
// pack = src | (dst&127)<<16  (src < 2^16)
__global__ __launch_bounds__(256) void k_bin(
    const void* __restrict__ ei_raw, const int* __restrict__ bbase,
    int* __restrict__ gcur, u32* __restrict__ bin) {
  __shared__ int cnt[NB];
  __shared__ u32 buf[NB * DEPTH];   // 25 KB
  int t = threadIdx.x;
  for (int i = t; i < NB; i += 256) cnt[i] = 0;
  __syncthreads();
  bool is64 = ei_is64(ei_raw);
  int base = blockIdx.x * EPB;
#pragma unroll
  for (int k = 0; k < 8; ++k) {
    int idx = base + k * 256 + t;
    if (idx >= NE) continue;
    int s, d;
    if (is64) {
      s = (int)((const long long*)ei_raw)[idx];
      d = (int)((const long long*)ei_raw)[NE + idx];
    } else {
      s = ((const int*)ei_raw)[idx];
      d = ((const int*)ei_raw)[NE + idx];
    }
    int b = d >> 7;
    u32 pack = (u32)s | ((u32)(d & 127) << 16);
    int p = atomicAdd(&cnt[b], 1);
    if (p < DEPTH) buf[b * DEPTH + p] = pack;
    else {               // rare overflow: direct scattered write
      int g = atomicAdd(&gcur[b], 1);
      bin[bbase[b] + g] = pack;
    }
  }
  __syncthreads();
  for (int b = t; b < NB; b += 256) {
    int c = min(cnt[b], DEPTH);
    if (c > 0) {
      int g = atomicAdd(&gcur[b], c);
      int gp = bbase[b] + g;
#pragma unroll 4
      for (int i = 0; i < c; ++i) bin[gp + i] = buf[b * DEPTH + i];
    }
  }
}

// ---- per-bucket CSR build + weight precompute -----------------------------
__global__ __launch_bounds__(256) void k_build(
    const int* __restrict__ bbase, const u32* __restrict__ bin,
    const float* __restrict__ a_src, const float* __restrict__ a_dst,
    int* __restrict__ rowptr, int* __restrict__ esrc, float* __restrict__ wgt) {
  __shared__ int cnt[128], bs[128], cur[128];
  __shared__ float aDl[128];
  int t = threadIdx.x;
  int b = blockIdx.x;
  int nbase = b << 7;
  int nmax = min(128, NN - nbase);
  int ebeg = bbase[b], eend = bbase[b + 1];
  int E = eend - ebeg;
  if (t < 128) { cnt[t] = 0; if (t < nmax) aDl[t] = a_dst[nbase + t]; }
  __syncthreads();
  for (int i = t; i < E; i += 256)
    atomicAdd(&cnt[bin[ebeg + i] >> 16], 1);
  __syncthreads();
  if (t < 128) bs[t] = cnt[t];
  __syncthreads();
  for (int off = 1; off < 128; off <<= 1) {
    int xv = (t < 128 && t >= off) ? bs[t - off] : 0;
    __syncthreads();
    if (t < 128) bs[t] += xv;
    __syncthreads();
  }
  if (t < 128) {
    int ex = bs[t] - cnt[t];      // inclusive -> exclusive
    bs[t] = ex;
    cur[t] = 0;
    if (t < nmax) rowptr[nbase + t] = ebeg + ex;
  }
  if (b == NB - 1 && t == 0) rowptr[NN] = NE;
  __syncthreads();
  for (int i = t; i < E; i += 256) {
    u32 e = bin[ebeg + i];
    int s = e & 0xFFFF;
    int ld = e >> 16;
    int p = atomicAdd(&cur[ld], 1);
    int pos = ebeg + bs[ld] + p;          // within L2-resident 8KB window
    esrc[pos] = s;
    wgt[pos] = __expf(leaky(a_src[s] + aDl[ld]));
  }
}

// ---- per-dst gather, wave-per-node, 4-way-unrolled shuffle-broadcast ------
__global__ __launch_bounds__(256) void k_aggregate(
    const int* __restrict__ rowptr, const int* __restrict__ esrc,
    const float* __restrict__ wgt, const float* __restrict__ a_src,
    const float* __restrict__ a_dst, const u16* __restrict__ h,
    float* __restrict__ accum) {
  int d = blockIdx.x * 4 + (threadIdx.x >> 6);
  if (d >= NN) return;
  int l = threadIdx.x & 63;            // lane owns channels 2l, 2l+1
  int beg = rowptr[d], end = rowptr[d + 1];

  float2 ac0 = make_float2(0.f, 0.f), ac1 = ac0, ac2 = ac0, ac3 = ac0;
  float wpart = 0.f;

  for (int j0 = beg; j0 < end; j0 += 64) {
    int n = min(64, end - j0);
    int s = 0;
    float w = 0.f;
    if (l < n) {
      s = esrc[j0 + l];
      w = wgt[j0 + l];
      wpart += w;
    }
    int jj = 0;
    for (; jj + 4 <= n; jj += 4) {
      int s0 = __shfl(s, jj),     s1 = __shfl(s, jj + 1);
      int s2 = __shfl(s, jj + 2), s3 = __shfl(s, jj + 3);
      float w0 = __shfl(w, jj),     w1 = __shfl(w, jj + 1);
      float w2 = __shfl(w, jj + 2), w3 = __shfl(w, jj + 3);
      u32 h0 = *(const u32*)&h[(size_t)s0 * NC + 2 * l];
      u32 h1 = *(const u32*)&h[(size_t)s1 * NC + 2 * l];
      u32 h2 = *(const u32*)&h[(size_t)s2 * NC + 2 * l];
      u32 h3 = *(const u32*)&h[(size_t)s3 * NC + 2 * l];
      ac0.x += w0 * blo(h0); ac0.y += w0 * bhi(h0);
      ac1.x += w1 * blo(h1); ac1.y += w1 * bhi(h1);
      ac2.x += w2 * blo(h2); ac2.y += w2 * bhi(h2);
      ac3.x += w3 * blo(h3); ac3.y += w3 * bhi(h3);
    }
    for (; jj < n; ++jj) {
      int sj = __shfl(s, jj);
      float wj = __shfl(w, jj);
      u32 hw = *(const u32*)&h[(size_t)sj * NC + 2 * l];
      ac0.x += wj * blo(hw); ac0.y += wj * bhi(hw);
    }
  }

  for (int off = 32; off > 0; off >>= 1) wpart += __shfl_xor(wpart, off);

  // self loop
  float wself = __expf(leaky(a_src[d] + a_dst[d]));
  u32 hw = *(const u32*)&h[(size_t)d * NC + 2 * l];
  float accx = ac0.x + ac1.x + ac2.x + ac3.x + wself * blo(hw);
  float accy = ac0.y + ac1.y + ac2.y + ac3.y + wself * bhi(hw);

  float inv = 1.f / (wpart + wself);
  *(float2*)&accum[(size_t)d * NC + 2 * l] = make_float2(accx * inv, accy * inv);
}

// ---- per-channel sum / sumsq (float4 per thread) --------------------------
__global__ __launch_bounds__(256) void k_stats(
    const float* __restrict__ accum, float* __restrict__ gsum,
    float* __restrict__ gsumsq) {
  __shared__ f32x4 sh[256], sh2[256];
  int t = threadIdx.x;
  int c4 = (t & 31) * 4;          // channel base
  int rg = t >> 5;                // row group 0..7
  f32x4 s = (f32x4){0.f,0.f,0.f,0.f}, ss = s;
  for (int row = blockIdx.x * 8 + rg; row < NN; row += gridDim.x * 8) {
    f32x4 v = *(const f32x4*)&accum[(size_t)row * NC + c4];
    s += v;
    ss += v * v;
  }
  sh[t] = s;
  sh2[t] = ss;
  __syncthreads();
  if (t < 32) {
    f32x4 a = sh[t], b = sh2[t];
#pragma unroll
    for (int g = 1; g < 8; ++g) { a += sh[g * 32 + t]; b += sh2[g * 32 + t]; }
#pragma unroll
    for (int j = 0; j < 4; ++j) {
      atomicAdd(&gsum[t * 4 + j], a[j]);
      atomicAdd(&gsumsq[t * 4 + j], b[j]);
    }
  }
}

// ---- BatchNorm (training stats) + ReLU -> fp32, float4 --------------------
__global__ __launch_bounds__(256) void k_bn(
    const float* __restrict__ accum, const float* __restrict__ gsum,
    const float* __restrict__ gsumsq, const float* __restrict__ gamma,
    const float* __restrict__ beta, float* __restrict__ out) {
  int i4 = blockIdx.x * 256 + threadIdx.x;
  if (i4 >= NN * NC / 4) return;
  int c4 = (i4 * 4) & 127;
  f32x4 gs = *(const f32x4*)&gsum[c4];
  f32x4 gq = *(const f32x4*)&gsumsq[c4];
  f32x4 ga = *(const f32x4*)&gamma[c4];
  f32x4 be = *(const f32x4*)&beta[c4];
  f32x4 v  = *(const f32x4*)&accum[(size_t)i4 * 4];
  f32x4 o;
#pragma unroll
  for (int j = 0; j < 4; ++j) {
    float mean = gs[j] * (1.0f / NN);
    float var = gq[j] * (1.0f / NN) - mean * mean;
    float inv = rsqrtf(var + BN_EPS);
    float y = (v[j] - mean) * inv * ga[j] + be[j];
    o[j] = (y > 0.f) ? y : 0.f;
  }
  *(f32x4*)&out[(size_t)i4 * 4] = o;
}

extern "C" void kernel_launch(void* const* d_in, const int* in_sizes, int n_in,
                              void* d_out, int out_size, void* d_ws, size_t ws_size,
                              hipStream_t stream) {
  const float* x    = (const float*)d_in[0];
  const void*  ei   = d_in[1];
  // d_in[2] = edge_attr (ignored: edge_dim=None in reference)
  const float* W    = (const float*)d_in[3];
  const float* attS = (const float*)d_in[4];
  const float* attD = (const float*)d_in[5];
  // d_in[6] = bias: cancels under BN mean-subtraction (and is zeros)
  const float* gamma = (const float*)d_in[7];
  const float* beta  = (const float*)d_in[8];

  float* ws     = (float*)d_ws;
  u16*   h      = (u16*)(ws + OFF_H);
  float* accum  = ws + OFF_ACCUM;
  float* a_src  = ws + OFF_ASRC;
  float* a_dst  = ws + OFF_ADST;
  int*   bcnt   = (int*)(ws + OFF_BCNT);
  int*   gcur   = (int*)(ws + OFF_GCUR);
  float* gsum   = ws + OFF_GSUM;
  float* gsumsq = ws + OFF_GSUMSQ;
  int*   bbase  = (int*)(ws + OFF_BBASE);
  int*   rowptr = (int*)(ws + OFF_ROWPTR);
  int*   esrc   = (int*)(ws + OFF_ESRC);
  float* wgt    = ws + OFF_WGT;
  u32*   bin    = (u32*)(ws + OFF_BIN);
  u32*   wb32   = (u32*)(ws + OFF_WB);

  const int nbin = (NE + EPB - 1) / EPB;  // 391
  // k_prep block 0 zeroes bcnt..gsumsq (NZERO words); no hipMemsetAsync needed.
  k_prep<<<8, 256, 0, stream>>>(W, wb32, bcnt);
  k_gemm<<<(NN + 127) / 128, 256, 0, stream>>>(x, (const u16*)wb32, attS, attD,
                                               h, a_src, a_dst);
  k_bhist<<<nbin, 256, 0, stream>>>(ei, bcnt);
  k_bscan<<<1, 512, 0, stream>>>(bcnt, bbase);
  k_bin<<<nbin, 256, 0, stream>>>(ei, bbase, gcur, bin);
  k_build<<<NB, 256, 0, stream>>>(bbase, bin, a_src, a_dst, rowptr, esrc, wgt);
  k_aggregate<<<(NN + 3) / 4, 256, 0, stream>>>(rowptr, esrc, wgt, a_src, a_dst, h, accum);
  k_stats<<<512, 256, 0, stream>>>(accum, gsum, gsumsq);
  k_bn<<<(NN * NC / 4 + 255) / 256, 256, 0, stream>>>(accum, gsum, gsumsq, gamma, beta,
                                                      (float*)d_out);
}

// Round 11
// 146.450 us; speedup vs baseline: 1.1226x; 1.1226x over previous
//
#include <hip/hip_runtime.h>
#include <hip/hip_bf16.h>

#define NN 50000
#define NE 800000
#define NC 128
#define NEG 0.2f
#define BN_EPS 1e-5f
#define NB 391           // ceil(NN/128) dst-buckets, 128 nodes each
#define EPB 2048         // edges per binning block
#define DEPTH 16         // LDS staging depth per bucket (flush = 64B line)
#define SBLK 512         // k_stats1 blocks
#define CHUNK 98         // ceil(NN/SBLK) rows per stats block

typedef unsigned int u32;
typedef unsigned short u16;
typedef short bf16x8 __attribute__((ext_vector_type(8)));
typedef float f32x4 __attribute__((ext_vector_type(4)));

// workspace layout (4-byte units)
#define OFF_H       0          // NN*NC bf16
#define OFF_ACCUM   3200000    // NN*NC f32
#define OFF_ASRC    9600000    // NN
#define OFF_ADST    9650000    // NN
#define OFF_BCNT    9700000    // 512   <- zeroed (in k_prep) from here
#define OFF_GCUR    9700512    // 512   <- zeroed to here (1024 words)
#define OFF_GSUM    9701024    // 128 (plain-stored by k_stats2)
#define OFF_GSUMSQ  9701152    // 128
#define OFF_BBASE   9701280    // 400 (NB+1)
#define OFF_ROWPTR  9701680    // NN+1
#define OFF_ESRC    9751688    // NE
#define OFF_WGT     10551688   // NE
#define OFF_BIN     11351688   // NE
#define OFF_WB      12151688   // 8192 u32 (W in bf16 MFMA-frag order, 32 KB)
#define OFF_PS      12159880   // SBLK*128 partial sums
#define OFF_PQ      12225416   // SBLK*128 partial sumsqs
#define OFF_END     12290952   // ~49.2 MB
#define NZERO       1024       // words zeroed each launch starting at OFF_BCNT

__device__ __forceinline__ float leaky(float e) { return (e >= 0.f) ? e : NEG * e; }

__device__ __forceinline__ u16 f2b(float f) {   // fp32 -> bf16 RNE
  union { float f; u32 u; } v; v.f = f;
  u32 u = v.u;
  return (u16)((u + 0x7fffu + ((u >> 16) & 1u)) >> 16);
}
__device__ __forceinline__ float blo(u32 u) {
  union { u32 u; float f; } v; v.u = u << 16; return v.f;
}
__device__ __forceinline__ float bhi(u32 u) {
  union { u32 u; float f; } v; v.u = u & 0xffff0000u; return v.f;
}

__device__ __forceinline__ bool ei_is64(const void* ei_raw) {
  const unsigned long long* p64 = (const unsigned long long*)ei_raw;
  bool is64 = true;
#pragma unroll
  for (int k = 0; k < 8; ++k) is64 = is64 && (p64[k] < (unsigned long long)NN);
  return is64;
}

// ---- pack W into MFMA B-fragment order (bf16) + zero the counter region ---
__global__ __launch_bounds__(256) void k_prep(
    const float* __restrict__ W, u32* __restrict__ Wb32, int* __restrict__ zbase) {
  if (blockIdx.x == 0) {
    for (int i = threadIdx.x; i < NZERO; i += 256) zbase[i] = 0;
  }
  int q = blockIdx.x * 256 + threadIdx.x;   // 2048 slots
  if (q >= 2048) return;
  int f = q >> 6, l = q & 63;
  int n = f >> 2, s = f & 3;
  int col = 16 * n + (l & 15);
  int kb = 32 * s + 8 * (l >> 4);
#pragma unroll
  for (int j2 = 0; j2 < 4; ++j2) {
    u16 e0 = f2b(W[(kb + 2 * j2) * NC + col]);
    u16 e1 = f2b(W[(kb + 2 * j2 + 1) * NC + col]);
    Wb32[q * 4 + j2] = ((u32)e1 << 16) | e0;
  }
}

// ---- h = x@W via MFMA bf16, B-frags from global (no LDS, no syncs) --------
__global__ __launch_bounds__(256) void k_gemm(
    const float* __restrict__ x, const u16* __restrict__ Wb,
    const float* __restrict__ attS, const float* __restrict__ attD,
    u16* __restrict__ h, float* __restrict__ a_src, float* __restrict__ a_dst) {
  const int t = threadIdx.x;
  const int l = t & 63;
  const int r0 = blockIdx.x * 128 + (t >> 6) * 32;
  const int lr = l & 15;                  // row-in-tile / col-in-frag
  const int kg = l >> 4;                  // k-group

  f32x4 acc[2][8];
#pragma unroll
  for (int t2 = 0; t2 < 2; ++t2)
#pragma unroll
    for (int n = 0; n < 8; ++n) acc[t2][n] = (f32x4){0.f, 0.f, 0.f, 0.f};

#pragma unroll
  for (int s = 0; s < 4; ++s) {
    bf16x8 bfr[8];
#pragma unroll
    for (int n = 0; n < 8; ++n)
      bfr[n] = *(const bf16x8*)(Wb + ((size_t)((n * 4 + s) * 64 + l)) * 8);

#pragma unroll
    for (int t2 = 0; t2 < 2; ++t2) {
      int arow = r0 + t2 * 16 + lr;
      f32x4 a0 = (f32x4){0.f,0.f,0.f,0.f}, a1 = a0;
      if (arow < NN) {
        const float* xa = x + (size_t)arow * NC + kg * 8 + s * 32;
        a0 = *(const f32x4*)xa;
        a1 = *(const f32x4*)(xa + 4);
      }
      bf16x8 af;
      af[0]=(short)f2b(a0[0]); af[1]=(short)f2b(a0[1]);
      af[2]=(short)f2b(a0[2]); af[3]=(short)f2b(a0[3]);
      af[4]=(short)f2b(a1[0]); af[5]=(short)f2b(a1[1]);
      af[6]=(short)f2b(a1[2]); af[7]=(short)f2b(a1[3]);
#pragma unroll
      for (int n = 0; n < 8; ++n)
        acc[t2][n] = __builtin_amdgcn_mfma_f32_16x16x32_bf16(af, bfr[n], acc[t2][n], 0, 0, 0);
    }
  }

  float attS_r[8], attD_r[8];
#pragma unroll
  for (int n = 0; n < 8; ++n) {
    attS_r[n] = attS[16 * n + lr];
    attD_r[n] = attD[16 * n + lr];
  }
#pragma unroll
  for (int t2 = 0; t2 < 2; ++t2) {
#pragma unroll
    for (int q = 0; q < 4; ++q) {
      int row = r0 + t2 * 16 + kg * 4 + q;
      bool rok = row < NN;
      float sA = 0.f, sD = 0.f;
#pragma unroll
      for (int n = 0; n < 8; ++n) {
        float v = acc[t2][n][q];
        sA += v * attS_r[n];
        sD += v * attD_r[n];
        if (rok) h[(size_t)row * NC + 16 * n + lr] = f2b(v);
      }
      sA += __shfl_xor(sA, 1); sD += __shfl_xor(sD, 1);
      sA += __shfl_xor(sA, 2); sD += __shfl_xor(sD, 2);
      sA += __shfl_xor(sA, 4); sD += __shfl_xor(sD, 4);
      sA += __shfl_xor(sA, 8); sD += __shfl_xor(sD, 8);
      if (lr == 0 && rok) { a_src[row] = sA; a_dst[row] = sD; }
    }
  }
}

// ---- bucket histogram (LDS-staged) ----------------------------------------
__global__ __launch_bounds__(256) void k_bhist(
    const void* __restrict__ ei_raw, int* __restrict__ bcnt) {
  __shared__ int cnt[NB];
  int t = threadIdx.x;
  for (int i = t; i < NB; i += 256) cnt[i] = 0;
  __syncthreads();
  bool is64 = ei_is64(ei_raw);
  int base = blockIdx.x * EPB;
#pragma unroll
  for (int k = 0; k < 8; ++k) {
    int idx = base + k * 256 + t;
    if (idx < NE) {
      int d = is64 ? (int)((const long long*)ei_raw)[NE + idx]
                   : ((const int*)ei_raw)[NE + idx];
      atomicAdd(&cnt[d >> 7], 1);
    }
  }
  __syncthreads();
  for (int i = t; i < NB; i += 256)
    if (cnt[i] > 0) atomicAdd(&bcnt[i], cnt[i]);
}

// ---- bucket-base exclusive scan (one block) -------------------------------
__global__ __launch_bounds__(512) void k_bscan(
    const int* __restrict__ bcnt, int* __restrict__ bbase) {
  __shared__ int sh[512];
  int t = threadIdx.x;
  int v = (t < NB) ? bcnt[t] : 0;
  sh[t] = v;
  __syncthreads();
  for (int off = 1; off < 512; off <<= 1) {
    int xv = (t >= off) ? sh[t - off] : 0;
    __syncthreads();
    sh[t] += xv;
    __syncthreads();
  }
  if (t <= NB) bbase[t] = sh[t] - v;   // exclusive; bbase[NB] = NE
}

// ---- bin edges into buckets, LDS-staged coalesced flushes -----------------
// pack = src | (dst&127)<<16  (src < 2^16)
__global__ __launch_bounds__(256) void k_bin(
    const void* __restrict__ ei_raw, const int* __restrict__ bbase,
    int* __restrict__ gcur, u32* __restrict__ bin) {
  __shared__ int cnt[NB];
  __shared__ u32 buf[NB * DEPTH];   // 25 KB
  int t = threadIdx.x;
  for (int i = t; i < NB; i += 256) cnt[i] = 0;
  __syncthreads();
  bool is64 = ei_is64(ei_raw);
  int base = blockIdx.x * EPB;
#pragma unroll
  for (int k = 0; k < 8; ++k) {
    int idx = base + k * 256 + t;
    if (idx >= NE) continue;
    int s, d;
    if (is64) {
      s = (int)((const long long*)ei_raw)[idx];
      d = (int)((const long long*)ei_raw)[NE + idx];
    } else {
      s = ((const int*)ei_raw)[idx];
      d = ((const int*)ei_raw)[NE + idx];
    }
    int b = d >> 7;
    u32 pack = (u32)s | ((u32)(d & 127) << 16);
    int p = atomicAdd(&cnt[b], 1);
    if (p < DEPTH) buf[b * DEPTH + p] = pack;
    else {               // rare overflow: direct scattered write
      int g = atomicAdd(&gcur[b], 1);
      bin[bbase[b] + g] = pack;
    }
  }
  __syncthreads();
  for (int b = t; b < NB; b += 256) {
    int c = min(cnt[b], DEPTH);
    if (c > 0) {
      int g = atomicAdd(&gcur[b], c);
      int gp = bbase[b] + g;
#pragma unroll 4
      for (int i = 0; i < c; ++i) bin[gp + i] = buf[b * DEPTH + i];
    }
  }
}

// ---- per-bucket CSR build + weight precompute -----------------------------
__global__ __launch_bounds__(256) void k_build(
    const int* __restrict__ bbase, const u32* __restrict__ bin,
    const float* __restrict__ a_src, const float* __restrict__ a_dst,
    int* __restrict__ rowptr, int* __restrict__ esrc, float* __restrict__ wgt) {
  __shared__ int cnt[128], bs[128], cur[128];
  __shared__ float aDl[128];
  int t = threadIdx.x;
  int b = blockIdx.x;
  int nbase = b << 7;
  int nmax = min(128, NN - nbase);
  int ebeg = bbase[b], eend = bbase[b + 1];
  int E = eend - ebeg;
  if (t < 128) { cnt[t] = 0; if (t < nmax) aDl[t] = a_dst[nbase + t]; }
  __syncthreads();
  for (int i = t; i < E; i += 256)
    atomicAdd(&cnt[bin[ebeg + i] >> 16], 1);
  __syncthreads();
  if (t < 128) bs[t] = cnt[t];
  __syncthreads();
  for (int off = 1; off < 128; off <<= 1) {
    int xv = (t < 128 && t >= off) ? bs[t - off] : 0;
    __syncthreads();
    if (t < 128) bs[t] += xv;
    __syncthreads();
  }
  if (t < 128) {
    int ex = bs[t] - cnt[t];      // inclusive -> exclusive
    bs[t] = ex;
    cur[t] = 0;
    if (t < nmax) rowptr[nbase + t] = ebeg + ex;
  }
  if (b == NB - 1 && t == 0) rowptr[NN] = NE;
  __syncthreads();
  for (int i = t; i < E; i += 256) {
    u32 e = bin[ebeg + i];
    int s = e & 0xFFFF;
    int ld = e >> 16;
    int p = atomicAdd(&cur[ld], 1);
    int pos = ebeg + bs[ld] + p;          // within L2-resident 8KB window
    esrc[pos] = s;
    wgt[pos] = __expf(leaky(a_src[s] + aDl[ld]));
  }
}

// ---- per-dst gather, wave-per-node, 4-way-unrolled shuffle-broadcast ------
__global__ __launch_bounds__(256) void k_aggregate(
    const int* __restrict__ rowptr, const int* __restrict__ esrc,
    const float* __restrict__ wgt, const float* __restrict__ a_src,
    const float* __restrict__ a_dst, const u16* __restrict__ h,
    float* __restrict__ accum) {
  int d = blockIdx.x * 4 + (threadIdx.x >> 6);
  if (d >= NN) return;
  int l = threadIdx.x & 63;            // lane owns channels 2l, 2l+1
  int beg = rowptr[d], end = rowptr[d + 1];

  float2 ac0 = make_float2(0.f, 0.f), ac1 = ac0, ac2 = ac0, ac3 = ac0;
  float wpart = 0.f;

  for (int j0 = beg; j0 < end; j0 += 64) {
    int n = min(64, end - j0);
    int s = 0;
    float w = 0.f;
    if (l < n) {
      s = esrc[j0 + l];
      w = wgt[j0 + l];
      wpart += w;
    }
    int jj = 0;
    for (; jj + 4 <= n; jj += 4) {
      int s0 = __shfl(s, jj),     s1 = __shfl(s, jj + 1);
      int s2 = __shfl(s, jj + 2), s3 = __shfl(s, jj + 3);
      float w0 = __shfl(w, jj),     w1 = __shfl(w, jj + 1);
      float w2 = __shfl(w, jj + 2), w3 = __shfl(w, jj + 3);
      u32 h0 = *(const u32*)&h[(size_t)s0 * NC + 2 * l];
      u32 h1 = *(const u32*)&h[(size_t)s1 * NC + 2 * l];
      u32 h2 = *(const u32*)&h[(size_t)s2 * NC + 2 * l];
      u32 h3 = *(const u32*)&h[(size_t)s3 * NC + 2 * l];
      ac0.x += w0 * blo(h0); ac0.y += w0 * bhi(h0);
      ac1.x += w1 * blo(h1); ac1.y += w1 * bhi(h1);
      ac2.x += w2 * blo(h2); ac2.y += w2 * bhi(h2);
      ac3.x += w3 * blo(h3); ac3.y += w3 * bhi(h3);
    }
    for (; jj < n; ++jj) {
      int sj = __shfl(s, jj);
      float wj = __shfl(w, jj);
      u32 hw = *(const u32*)&h[(size_t)sj * NC + 2 * l];
      ac0.x += wj * blo(hw); ac0.y += wj * bhi(hw);
    }
  }

  for (int off = 32; off > 0; off >>= 1) wpart += __shfl_xor(wpart, off);

  // self loop
  float wself = __expf(leaky(a_src[d] + a_dst[d]));
  u32 hw = *(const u32*)&h[(size_t)d * NC + 2 * l];
  float accx = ac0.x + ac1.x + ac2.x + ac3.x + wself * blo(hw);
  float accy = ac0.y + ac1.y + ac2.y + ac3.y + wself * bhi(hw);

  float inv = 1.f / (wpart + wself);
  *(float2*)&accum[(size_t)d * NC + 2 * l] = make_float2(accx * inv, accy * inv);
}

// ---- stats stage 1: per-block partial sums over a contiguous row chunk ----
__global__ __launch_bounds__(256) void k_stats1(
    const float* __restrict__ accum, float* __restrict__ partS,
    float* __restrict__ partQ) {
  __shared__ float sh[256], sh2[256];
  int t = threadIdx.x;
  int c = t & 127, rh = t >> 7;
  int r0 = blockIdx.x * CHUNK;
  int r1 = min(NN, r0 + CHUNK);
  float s = 0.f, ss = 0.f;
  for (int row = r0 + rh; row < r1; row += 2) {
    float v = accum[(size_t)row * NC + c];
    s += v;
    ss += v * v;
  }
  sh[t] = s;
  sh2[t] = ss;
  __syncthreads();
  if (t < 128) {
    partS[blockIdx.x * 128 + t] = sh[t] + sh[t + 128];
    partQ[blockIdx.x * 128 + t] = sh2[t] + sh2[t + 128];
  }
}

// ---- stats stage 2: reduce partials, plain-store gsum/gsumsq --------------
__global__ __launch_bounds__(256) void k_stats2(
    const float* __restrict__ partS, const float* __restrict__ partQ,
    float* __restrict__ gsum, float* __restrict__ gsumsq) {
  int t = threadIdx.x;
  int c = t & 127;
  const float* src = (t >> 7) ? partQ : partS;
  float a = 0.f;
#pragma unroll 8
  for (int i = 0; i < SBLK; ++i) a += src[i * 128 + c];
  if (t >> 7) gsumsq[c] = a;
  else        gsum[c] = a;
}

// ---- BatchNorm (training stats) + ReLU -> fp32, float4 --------------------
__global__ __launch_bounds__(256) void k_bn(
    const float* __restrict__ accum, const float* __restrict__ gsum,
    const float* __restrict__ gsumsq, const float* __restrict__ gamma,
    const float* __restrict__ beta, float* __restrict__ out) {
  int i4 = blockIdx.x * 256 + threadIdx.x;
  if (i4 >= NN * NC / 4) return;
  int c4 = (i4 * 4) & 127;
  f32x4 gs = *(const f32x4*)&gsum[c4];
  f32x4 gq = *(const f32x4*)&gsumsq[c4];
  f32x4 ga = *(const f32x4*)&gamma[c4];
  f32x4 be = *(const f32x4*)&beta[c4];
  f32x4 v  = *(const f32x4*)&accum[(size_t)i4 * 4];
  f32x4 o;
#pragma unroll
  for (int j = 0; j < 4; ++j) {
    float mean = gs[j] * (1.0f / NN);
    float var = gq[j] * (1.0f / NN) - mean * mean;
    float inv = rsqrtf(var + BN_EPS);
    float y = (v[j] - mean) * inv * ga[j] + be[j];
    o[j] = (y > 0.f) ? y : 0.f;
  }
  *(f32x4*)&out[(size_t)i4 * 4] = o;
}

extern "C" void kernel_launch(void* const* d_in, const int* in_sizes, int n_in,
                              void* d_out, int out_size, void* d_ws, size_t ws_size,
                              hipStream_t stream) {
  const float* x    = (const float*)d_in[0];
  const void*  ei   = d_in[1];
  // d_in[2] = edge_attr (ignored: edge_dim=None in reference)
  const float* W    = (const float*)d_in[3];
  const float* attS = (const float*)d_in[4];
  const float* attD = (const float*)d_in[5];
  // d_in[6] = bias: cancels under BN mean-subtraction (and is zeros)
  const float* gamma = (const float*)d_in[7];
  const float* beta  = (const float*)d_in[8];

  float* ws     = (float*)d_ws;
  u16*   h      = (u16*)(ws + OFF_H);
  float* accum  = ws + OFF_ACCUM;
  float* a_src  = ws + OFF_ASRC;
  float* a_dst  = ws + OFF_ADST;
  int*   bcnt   = (int*)(ws + OFF_BCNT);
  int*   gcur   = (int*)(ws + OFF_GCUR);
  float* gsum   = ws + OFF_GSUM;
  float* gsumsq = ws + OFF_GSUMSQ;
  int*   bbase  = (int*)(ws + OFF_BBASE);
  int*   rowptr = (int*)(ws + OFF_ROWPTR);
  int*   esrc   = (int*)(ws + OFF_ESRC);
  float* wgt    = ws + OFF_WGT;
  u32*   bin    = (u32*)(ws + OFF_BIN);
  u32*   wb32   = (u32*)(ws + OFF_WB);
  float* partS  = ws + OFF_PS;
  float* partQ  = ws + OFF_PQ;

  const int nbin = (NE + EPB - 1) / EPB;  // 391
  // k_prep block 0 zeroes bcnt+gcur (NZERO words); gsum/gsumsq are plain-stored.
  k_prep<<<8, 256, 0, stream>>>(W, wb32, bcnt);
  k_gemm<<<(NN + 127) / 128, 256, 0, stream>>>(x, (const u16*)wb32, attS, attD,
                                               h, a_src, a_dst);
  k_bhist<<<nbin, 256, 0, stream>>>(ei, bcnt);
  k_bscan<<<1, 512, 0, stream>>>(bcnt, bbase);
  k_bin<<<nbin, 256, 0, stream>>>(ei, bbase, gcur, bin);
  k_build<<<NB, 256, 0, stream>>>(bbase, bin, a_src, a_dst, rowptr, esrc, wgt);
  k_aggregate<<<(NN + 3) / 4, 256, 0, stream>>>(rowptr, esrc, wgt, a_src, a_dst, h, accum);
  k_stats1<<<SBLK, 256, 0, stream>>>(accum, partS, partQ);
  k_stats2<<<1, 256, 0, stream>>>(partS, partQ, gsum, gsumsq);
  k_bn<<<(NN * NC / 4 + 255) / 256, 256, 0, stream>>>(accum, gsum, gsumsq, gamma, beta,
                                                      (float*)d_out);
}